// Round 7
// baseline (385.505 us; speedup 1.0000x reference)
//
#include <hip/hip_runtime.h>
#include <math.h>

// Problem constants
#define N_PRED 1200      // bs*Q
#define N_TGT  200
#define T_PAD  208       // 13 tiles of 16
#define NCLS   80
#define W_OUT  160
#define W_IN   320
#define HW     25600     // 160*160 == K of the GEMMs
#define K_TOT  25600
#define KS     40        // K-split factor (grid 760)
#define K_CHUNK 640      // K_TOT / KS
#define BK     64        // K per iteration (2 MFMA k-steps)
#define NI     (K_CHUNK / BK)
#define MT     19        // ceil(1200/64) M-tiles of 64
#define PROW   (2 * T_PAD)   // interleaved {S,X} partial row stride (floats)

// Round-6 lesson: the 2-barrier LDS-staged K-loop is structurally stall-bound
// (vmcnt(0) drain at every barrier; CONVW lock-stepped between barriers).
// This version has NO barriers and NO LDS: each lane loads its own MFMA
// A-fragment (contiguous 8 fp32), converts in registers; B-fragments read
// directly from global (L2-resident, 16 rows x 64 B per instr), grouped and
// prefetched 2 MFMA-groups ahead. Pure dataflow + vmcnt waterfall.

typedef __bf16 bf16x8 __attribute__((ext_vector_type(8)));
typedef float  f32x4  __attribute__((ext_vector_type(4)));

__device__ __forceinline__ unsigned short f2bf(float f) {
    unsigned int u = __float_as_uint(f);
    u = u + 0x7FFFu + ((u >> 16) & 1u);   // round-to-nearest-even
    return (unsigned short)(u >> 16);
}

#if __has_builtin(__builtin_amdgcn_cvt_pk_bf16_f32)
typedef __bf16 bf16x2 __attribute__((ext_vector_type(2)));
__device__ __forceinline__ unsigned pk_bf16(float a, float b) {
    bf16x2 v = __builtin_amdgcn_cvt_pk_bf16_f32(a, b);
    return *(unsigned*)&v;
}
#else
__device__ __forceinline__ unsigned pk_bf16(float a, float b) {
    return (unsigned)f2bf(a) | ((unsigned)f2bf(b) << 16);
}
#endif

// jax.image.resize(antialias=True, bilinear, 320->160): 4 taps, weights
// {1,3,3,1}/8 interior; boundary renormalized ({3,3,1}/7).
__device__ __forceinline__ void taps(int i, int& i0, float w[4]) {
    if (i == 0)            { i0 = 0;       w[0]=3.f/7.f; w[1]=3.f/7.f; w[2]=1.f/7.f; w[3]=0.f; }
    else if (i == W_OUT-1) { i0 = 2*i - 2; w[0]=0.f;     w[1]=1.f/7.f; w[2]=3.f/7.f; w[3]=3.f/7.f; }
    else                   { i0 = 2*i - 1; w[0]=0.125f;  w[1]=0.375f;  w[2]=0.375f;  w[3]=0.125f; }
}

// K1 prep: resize tgt masks -> bf16 [T_PAD][25600] + per-quarter colsums
// + zero sig_rs/l1p_rs in the pad-row blocks. grid (4, T_PAD) x 256.
__global__ void prep_kernel(const float* __restrict__ tm,
                            unsigned short* __restrict__ tgt_bf,
                            float* __restrict__ tgt_sumP,   // [4][T_PAD]
                            float* __restrict__ sig_rs,     // [N_PRED] zeroed here
                            float* __restrict__ l1p_rs) {   // [N_PRED] zeroed here
    const int t = blockIdx.y, q = blockIdx.x, tid = threadIdx.x;
    if (t >= N_TGT) {   // zero pad rows of B + zero the rowsum arrays (ws is 0xAA)
        uint4 z = make_uint4(0,0,0,0);
        uint4* dst = (uint4*)(tgt_bf + (size_t)t * HW) + q * (HW/8/4);
        for (int u = tid; u < HW/8/4; u += 256) dst[u] = z;
        if (q == 0) {
            const int base = (t - N_TGT) * 150;   // 8 blocks x 150 = 1200
            if (tid < 150) { sig_rs[base + tid] = 0.f; l1p_rs[base + tid] = 0.f; }
        }
        if (tid == 0) tgt_sumP[q * T_PAD + t] = 0.f;
        return;
    }
    const float* src = tm + (size_t)t * (W_IN * W_IN);
    float part = 0.f;
    const int p0 = q * (HW/4);
    for (int pp = tid; pp < HW/4; pp += 256) {
        const int p = p0 + pp;
        const int i = p / W_OUT, j = p % W_OUT;
        int r0, c0; float wr[4], wc[4];
        taps(i, r0, wr); taps(j, c0, wc);
        float v = 0.f;
        #pragma unroll
        for (int a = 0; a < 4; a++) {
            const float* row = src + (size_t)(r0 + a) * W_IN + c0;
            float h = wc[0]*row[0] + wc[1]*row[1] + wc[2]*row[2] + wc[3]*row[3];
            v += wr[a] * h;
        }
        tgt_bf[(size_t)t * HW + p] = f2bf(v);
        part += v;
    }
    __shared__ float red[256];
    red[tid] = part; __syncthreads();
    for (int s = 128; s > 0; s >>= 1) { if (tid < s) red[tid] += red[tid + s]; __syncthreads(); }
    if (tid == 0) tgt_sumP[q * T_PAD + t] = red[0];
}

// ---- K2: barrier-free dual GEMM, all fragments via registers ----
#define DECL13(p) f32x4 p##0={0,0,0,0}, p##1={0,0,0,0}, p##2={0,0,0,0}, p##3={0,0,0,0}, \
    p##4={0,0,0,0}, p##5={0,0,0,0}, p##6={0,0,0,0}, p##7={0,0,0,0}, p##8={0,0,0,0}, \
    p##9={0,0,0,0}, p##10={0,0,0,0}, p##11={0,0,0,0}, p##12={0,0,0,0}

// B fragment load: lane reads tgt[t = tt*16 + l16][k .. k+8) at quad*8 (in bp)
#define LB(dst, tt, kof) dst = *(const uint4*)(bp + (tt)*16*K_TOT + (kof));

// dual MFMA on one t-tile
#define MF(tt, BREG, AX, AS) { const bf16x8 bv = *(const bf16x8*)&BREG; \
    accS##tt = __builtin_amdgcn_mfma_f32_16x16x32_bf16(AS, bv, accS##tt, 0, 0, 0); \
    accX##tt = __builtin_amdgcn_mfma_f32_16x16x32_bf16(AX, bv, accX##tt, 0, 0, 0); }

// convert 8 contiguous fp32 (two float4) -> bf16 X-frag + bf16 sigma-frag,
// accumulate rowsums. |x|<~7: exp(-x) finite; softplus(x) = x + log(1+exp(-x)).
#define CONV8(A0, A1, FX, FS) { \
    const float x0=A0.x, x1=A0.y, x2=A0.z, x3=A0.w; \
    const float x4=A1.x, x5=A1.y, x6=A1.z, x7=A1.w; \
    const float e0=__expf(-x0), e1=__expf(-x1), e2=__expf(-x2), e3=__expf(-x3); \
    const float e4=__expf(-x4), e5=__expf(-x5), e6=__expf(-x6), e7=__expf(-x7); \
    const float u0=1.f+e0, u1=1.f+e1, u2=1.f+e2, u3=1.f+e3; \
    const float u4=1.f+e4, u5=1.f+e5, u6=1.f+e6, u7=1.f+e7; \
    const float s0=__builtin_amdgcn_rcpf(u0), s1=__builtin_amdgcn_rcpf(u1); \
    const float s2=__builtin_amdgcn_rcpf(u2), s3=__builtin_amdgcn_rcpf(u3); \
    const float s4=__builtin_amdgcn_rcpf(u4), s5=__builtin_amdgcn_rcpf(u5); \
    const float s6=__builtin_amdgcn_rcpf(u6), s7=__builtin_amdgcn_rcpf(u7); \
    sS += ((s0+s1)+(s2+s3)) + ((s4+s5)+(s6+s7)); \
    sL -= ((x0+__logf(u0)) + (x1+__logf(u1)) + (x2+__logf(u2)) + (x3+__logf(u3))) \
        + ((x4+__logf(u4)) + (x5+__logf(u5)) + (x6+__logf(u6)) + (x7+__logf(u7))); \
    uint4 tx = make_uint4(pk_bf16(x0,x1), pk_bf16(x2,x3), pk_bf16(x4,x5), pk_bf16(x6,x7)); \
    uint4 ts = make_uint4(pk_bf16(s0,s1), pk_bf16(s2,s3), pk_bf16(s4,s5), pk_bf16(s6,s7)); \
    FX = *(bf16x8*)&tx; FS = *(bf16x8*)&ts; }

// epilogue: C/D layout col=lane&15, row=quad*4+reg; interleaved {S,X} float2
#define EPI(tt) { const size_t b0 = base + (size_t)(wave * 16 + quad * 4) * PROW + 2 * ((tt) * 16 + l16); \
    *(float2*)&P[b0           ] = make_float2(accS##tt[0], accX##tt[0]); \
    *(float2*)&P[b0 +     PROW] = make_float2(accS##tt[1], accX##tt[1]); \
    *(float2*)&P[b0 + 2 * PROW] = make_float2(accS##tt[2], accX##tt[2]); \
    *(float2*)&P[b0 + 3 * PROW] = make_float2(accS##tt[3], accX##tt[3]); }

__global__ __launch_bounds__(256, 2)
void gemm_kernel(const float* __restrict__ pm,
                 const unsigned short* __restrict__ tgt_bf,
                 float* __restrict__ P,
                 float* __restrict__ sig_rs, float* __restrict__ l1p_rs) {
    const int ks = blockIdx.x, mtile = blockIdx.y;
    const int tid = threadIdx.x;
    const int wave = tid >> 6, lane = tid & 63;
    const int quad = lane >> 4, l16 = lane & 15;

    DECL13(accS);
    DECL13(accX);
    float sS = 0.f, sL = 0.f;

    const int m0 = mtile * 64;
    const int k0 = ks * K_CHUNK;

    // A: this lane's MFMA fragment rows are m = m0 + wave*16 + l16, k = quad*8 + j
    const int rg = m0 + wave * 16 + l16;           // unclamped (rowsum guard)
    int rowi = rg; if (rowi > N_PRED - 1) rowi = N_PRED - 1;
    const float* ap = pm + (size_t)rowi * K_TOT + quad * 8;
    // B: lane reads t-row (tt*16 + l16), k offset quad*8
    const unsigned short* bp = tgt_bf + (size_t)l16 * K_TOT + quad * 8;

    // ---- prologue: A for iter 0, B group (tt 0-6, kk=0) for iter 0 ----
    float4 A0 = *(const float4*)(ap + k0);
    float4 A1 = *(const float4*)(ap + k0 + 4);
    float4 A2 = *(const float4*)(ap + k0 + 32);
    float4 A3 = *(const float4*)(ap + k0 + 36);
    uint4 b0, b1, b2, b3, b4, b5, b6;
    uint4 c0, c1, c2, c3, c4, c5;
    LB(b0, 0, k0); LB(b1, 1, k0); LB(b2, 2, k0); LB(b3, 3, k0);
    LB(b4, 4, k0); LB(b5, 5, k0); LB(b6, 6, k0);

    for (int ki = 0; ki < NI; ki++) {
        const int k = k0 + ki * BK;
        bf16x8 aX0, aS0, aX1, aS1;
        CONV8(A0, A1, aX0, aS0);       // kk=0 fragment
        CONV8(A2, A3, aX1, aS1);       // kk=1 fragment
        // issue second B group (tt 7-12, kk=0)
        LB(c0, 7, k); LB(c1, 8, k); LB(c2, 9, k);
        LB(c3, 10, k); LB(c4, 11, k); LB(c5, 12, k);
        // prefetch next iteration's A early (covered by 4 MFMA groups)
        if (ki != NI - 1) {
            A0 = *(const float4*)(ap + k + BK);
            A1 = *(const float4*)(ap + k + BK + 4);
            A2 = *(const float4*)(ap + k + BK + 32);
            A3 = *(const float4*)(ap + k + BK + 36);
        }
        // group 1: tt 0-6, kk=0 (b*, loaded long ago)
        MF(0, b0, aX0, aS0); MF(1, b1, aX0, aS0); MF(2, b2, aX0, aS0);
        MF(3, b3, aX0, aS0); MF(4, b4, aX0, aS0); MF(5, b5, aX0, aS0);
        MF(6, b6, aX0, aS0);
        // reload b* for kk=1
        LB(b0, 0, k + 32); LB(b1, 1, k + 32); LB(b2, 2, k + 32); LB(b3, 3, k + 32);
        LB(b4, 4, k + 32); LB(b5, 5, k + 32); LB(b6, 6, k + 32);
        // group 2: tt 7-12, kk=0 (c*)
        MF(7, c0, aX0, aS0); MF(8, c1, aX0, aS0); MF(9, c2, aX0, aS0);
        MF(10, c3, aX0, aS0); MF(11, c4, aX0, aS0); MF(12, c5, aX0, aS0);
        // reload c* for kk=1
        LB(c0, 7, k + 32); LB(c1, 8, k + 32); LB(c2, 9, k + 32);
        LB(c3, 10, k + 32); LB(c4, 11, k + 32); LB(c5, 12, k + 32);
        // group 3: tt 0-6, kk=1 (b*)
        MF(0, b0, aX1, aS1); MF(1, b1, aX1, aS1); MF(2, b2, aX1, aS1);
        MF(3, b3, aX1, aS1); MF(4, b4, aX1, aS1); MF(5, b5, aX1, aS1);
        MF(6, b6, aX1, aS1);
        // prefetch next iteration's first B group (tt 0-6, kk=0)
        if (ki != NI - 1) {
            LB(b0, 0, k + BK); LB(b1, 1, k + BK); LB(b2, 2, k + BK); LB(b3, 3, k + BK);
            LB(b4, 4, k + BK); LB(b5, 5, k + BK); LB(b6, 6, k + BK);
        }
        // group 4: tt 7-12, kk=1 (c*)
        MF(7, c0, aX1, aS1); MF(8, c1, aX1, aS1); MF(9, c2, aX1, aS1);
        MF(10, c3, aX1, aS1); MF(11, c4, aX1, aS1); MF(12, c5, aX1, aS1);
    }

    // partial-C epilogue
    const size_t base = ((size_t)(mtile * KS + ks)) * 64 * PROW;
    EPI(0); EPI(1); EPI(2); EPI(3); EPI(4); EPI(5); EPI(6);
    EPI(7); EPI(8); EPI(9); EPI(10); EPI(11); EPI(12);

    // rowsums: lane covers row rg over its quad's k-slice; reduce across quads
    sS += __shfl_xor(sS, 16); sS += __shfl_xor(sS, 32);
    sL += __shfl_xor(sL, 16); sL += __shfl_xor(sL, 32);
    if (quad == 0 && rg < N_PRED) {
        atomicAdd(sig_rs + rg, sS);
        atomicAdd(l1p_rs + rg, sL);
    }
}

// K3: reduce K-split partials + class/bbox/giou + assemble final cost.
__global__ void combine_kernel(const float* __restrict__ pred_logits,
                               const float* __restrict__ pred_boxes,
                               const int*   __restrict__ tgt_ids,
                               const float* __restrict__ tgt_bbox,
                               const float* __restrict__ P,
                               const float* __restrict__ sig_rs, const float* __restrict__ l1p_rs,
                               const float* __restrict__ tgt_sumP,
                               float* __restrict__ out) {
    const int e = blockIdx.x * 256 + threadIdx.x;
    if (e >= N_PRED * N_TGT) return;
    const int n = e / N_TGT, t = e - n * N_TGT;
    const int mtile = n >> 6, mrow = n & 63;

    const size_t pb = ((size_t)mtile * KS * 64 + mrow) * PROW + 2 * t;
    float s1 = 0.f, s2 = 0.f;
    for (int ks = 0; ks < KS; ks++) {
        float2 v = *(const float2*)&P[pb + (size_t)ks * 64 * PROW];
        s1 += v.x; s2 += v.y;
    }
    // dice
    const float tsum = tgt_sumP[t] + tgt_sumP[T_PAD + t] + tgt_sumP[2*T_PAD + t] + tgt_sumP[3*T_PAD + t];
    const float denom = sig_rs[n] + tsum;
    const float cost_dice = -(2.f * s1 + 1.f) / (fmaxf(denom, 1e-6f) + 1.f);
    // mask BCE: -(S2 + rowsum(log_1mp))/HW
    const float cost_mask = -(s2 + l1p_rs[n]) / (float)HW;
    // class
    const int id = tgt_ids[t];
    const float lg = pred_logits[(size_t)n * NCLS + id];
    const float p = 1.f / (1.f + __expf(-lg));
    // bbox L1
    const float4 ob = *(const float4*)(pred_boxes + (size_t)n * 4);
    const float4 tb = *(const float4*)(tgt_bbox + (size_t)t * 4);
    const float l1 = fabsf(ob.x - tb.x) + fabsf(ob.y - tb.y) + fabsf(ob.z - tb.z) + fabsf(ob.w - tb.w);
    // giou
    const float ax0 = ob.x - 0.5f*ob.z, ay0 = ob.y - 0.5f*ob.w;
    const float ax1 = ob.x + 0.5f*ob.z, ay1 = ob.y + 0.5f*ob.w;
    const float bx0 = tb.x - 0.5f*tb.z, by0 = tb.y - 0.5f*tb.w;
    const float bx1 = tb.x + 0.5f*tb.z, by1 = tb.y + 0.5f*tb.w;
    const float areaA = (ax1 - ax0) * (ay1 - ay0);
    const float areaB = (bx1 - bx0) * (by1 - by0);
    const float iw = fmaxf(fminf(ax1, bx1) - fmaxf(ax0, bx0), 0.f);
    const float ih = fmaxf(fminf(ay1, by1) - fmaxf(ay0, by0), 0.f);
    const float inter = iw * ih;
    const float uni = areaA + areaB - inter;
    const float iou = inter / uni;
    const float cw = fmaxf(fmaxf(ax1, bx1) - fminf(ax0, bx0), 0.f);
    const float ch = fmaxf(fmaxf(ay1, by1) - fminf(ay0, by0), 0.f);
    const float areaC = cw * ch;
    const float giou = iou - (areaC - uni) / areaC;

    out[e] = 5.f * l1 + 2.f * (-giou) + 2.f * (-p) + 2.f * cost_mask + 2.f * cost_dice;
}

extern "C" void kernel_launch(void* const* d_in, const int* in_sizes, int n_in,
                              void* d_out, int out_size, void* d_ws, size_t ws_size,
                              hipStream_t stream) {
    const float* pred_logits = (const float*)d_in[0];
    const float* pred_boxes  = (const float*)d_in[1];
    const float* pred_masks  = (const float*)d_in[2];
    const int*   tgt_ids     = (const int*)d_in[3];
    const float* tgt_bbox    = (const float*)d_in[4];
    const float* tgt_masks   = (const float*)d_in[5];
    float* out = (float*)d_out;

    // workspace carving (~92 MB; ws_size ~491 MB per harness fill counters)
    char* ws = (char*)d_ws;
    size_t off = 0;
    unsigned short* tgt_bf = (unsigned short*)(ws + off);
    off += (size_t)T_PAD * K_TOT * sizeof(unsigned short);       // 10,649,600
    off = (off + 255) & ~(size_t)255;
    float* tgt_sumP = (float*)(ws + off);                         // [4][208]
    float* sig_rs   = tgt_sumP + 4 * T_PAD;                       // [1200]
    float* l1p_rs   = sig_rs + N_PRED;                            // [1200]
    off += (size_t)(4 * T_PAD + 2 * N_PRED) * sizeof(float);
    off = (off + 255) & ~(size_t)255;
    float* P = (float*)(ws + off);                                // interleaved partials
    off += (size_t)MT * KS * 64 * PROW * sizeof(float);           // 80,936,960

    hipLaunchKernelGGL(prep_kernel, dim3(4, T_PAD), dim3(256), 0, stream,
                       tgt_masks, tgt_bf, tgt_sumP, sig_rs, l1p_rs);
    hipLaunchKernelGGL(gemm_kernel, dim3(KS, MT), dim3(256), 0, stream,
                       pred_masks, tgt_bf, P, sig_rs, l1p_rs);
    hipLaunchKernelGGL(combine_kernel, dim3((N_PRED * N_TGT + 255) / 256), dim3(256), 0, stream,
                       pred_logits, pred_boxes, tgt_ids, tgt_bbox,
                       P, sig_rs, l1p_rs, tgt_sumP, out);
}

// Round 8
// 311.211 us; speedup vs baseline: 1.2387x; 1.2387x over previous
//
#include <hip/hip_runtime.h>
#include <math.h>

// Problem constants
#define N_PRED 1200      // bs*Q
#define N_TGT  200
#define T_PAD  208       // 13 tiles of 16
#define NCLS   80
#define W_OUT  160
#define W_IN   320
#define HW     25600
#define K_TOT  25600
#define KS     25        // K-split (grid 475; r6 showed KS=40 worse)
#define K_CHUNK 1024
#define BK     128       // K per LDS stage (8 iters -> half the barrier drains of r4)
#define NI     (K_CHUNK / BK)
#define MT     19
#define MROWS  2432      // MT*128 fp8 plane rows (2 per pred, padded)
#define PROW   (2 * T_PAD)

// Design (r7 post-mortem): conversion OUT of the K-loop (fp8 planes precomputed),
// GEMM = lean m97-style global_load_lds fp8 MFMA with BK=128.
// Global-side swizzle: within each 64B k-block of a row R, 8B group g is stored
// at position g ^ ((R>>1)&7). Linear DMA then yields LDS fragments whose
// ds_read_b64 bank usage is evenly spread (throughput floor).

typedef float f32x4 __attribute__((ext_vector_type(4)));

__device__ __forceinline__ unsigned char enc_e4m3(float x) {   // fallback only
    unsigned b = __float_as_uint(x);
    unsigned sgn = (b >> 24) & 0x80;
    float a = fabsf(x);
    if (a >= 448.f) return (unsigned char)(sgn | 0x7E);
    if (a < 0.0009765625f) return (unsigned char)sgn;
    int e = (int)((b >> 23) & 255) - 127;
    if (e < -6) {
        int mi = (int)(a * 512.f + 0.5f);
        if (mi >= 8) return (unsigned char)(sgn | 0x08);
        return (unsigned char)(sgn | mi);
    }
    unsigned m = b & 0x7FFFFF;
    unsigned rb = m + 0x7FFFF + ((m >> 20) & 1);
    if (rb & 0x800000) { e++; rb = 0; }
    if (e > 8) return (unsigned char)(sgn | 0x7E);
    return (unsigned char)(sgn | ((unsigned)(e + 7) << 3) | ((rb >> 20) & 7));
}

__device__ __forceinline__ unsigned pk4_fp8(float a, float b, float c, float d) {
#if __has_builtin(__builtin_amdgcn_cvt_pk_fp8_f32)
    int w = __builtin_amdgcn_cvt_pk_fp8_f32(a, b, 0, false);
    w = __builtin_amdgcn_cvt_pk_fp8_f32(c, d, w, true);
    return (unsigned)w;
#else
    return (unsigned)enc_e4m3(a) | ((unsigned)enc_e4m3(b) << 8) |
           ((unsigned)enc_e4m3(c) << 16) | ((unsigned)enc_e4m3(d) << 24);
#endif
}

__device__ __forceinline__ void gld16(const void* g, void* l) {
    __builtin_amdgcn_global_load_lds(
        (const __attribute__((address_space(1))) void*)g,
        (__attribute__((address_space(3))) void*)l, 16, 0, 0);
}

// swizzled byte position of 4-aligned element group k0c within a row
__device__ __forceinline__ int swpos(int k0c, int key) {
    const int b = k0c >> 6, g = (k0c >> 3) & 7;
    return b * 64 + ((g ^ key) * 8) + (k0c & 4);
}

// jax.image.resize(antialias=True, bilinear, 320->160): {1,3,3,1}/8 interior,
// boundary renormalized {3,3,1}/7.
__device__ __forceinline__ void taps(int i, int& i0, float w[4]) {
    if (i == 0)            { i0 = 0;       w[0]=3.f/7.f; w[1]=3.f/7.f; w[2]=1.f/7.f; w[3]=0.f; }
    else if (i == W_OUT-1) { i0 = 2*i - 2; w[0]=0.f;     w[1]=1.f/7.f; w[2]=3.f/7.f; w[3]=3.f/7.f; }
    else                   { i0 = 2*i - 1; w[0]=0.125f;  w[1]=0.375f;  w[2]=0.375f;  w[3]=0.125f; }
}

// K0: pred_masks fp32 -> fp8 planes A2[2n]=sigma_n, A2[2n+1]=x_n (swizzled),
// plus exact fp32 rowsums. grid 1216 x 256. Pads (n>=1200) zeroed.
__global__ void conv_kernel(const float* __restrict__ pm,
                            unsigned char* __restrict__ A2,
                            float* __restrict__ sig_rs,
                            float* __restrict__ l1p_rs) {
    const int n = blockIdx.x, tid = threadIdx.x;
    if (n >= N_PRED) {   // zero the 2 pad rows (ws poisoned 0xAA)
        uint4 z = make_uint4(0,0,0,0);
        uint4* dst = (uint4*)(A2 + (size_t)(2*n) * K_TOT);
        for (int i = tid; i < 3200; i += 256) dst[i] = z;
        return;
    }
    const float* row = pm + (size_t)n * K_TOT;
    unsigned char* rS = A2 + (size_t)(2*n) * K_TOT;
    unsigned char* rX = rS + K_TOT;
    const int key = n & 7;                 // (R>>1)&7, same for both planes
    float sS = 0.f, sL = 0.f;
    #pragma unroll
    for (int j = 0; j < 25; j++) {
        const int k0c = tid * 4 + j * 1024;
        float4 x = *(const float4*)(row + k0c);
        const float e0=__expf(-x.x), e1=__expf(-x.y), e2=__expf(-x.z), e3=__expf(-x.w);
        const float u0=1.f+e0, u1=1.f+e1, u2=1.f+e2, u3=1.f+e3;
        const float s0=__builtin_amdgcn_rcpf(u0), s1=__builtin_amdgcn_rcpf(u1);
        const float s2=__builtin_amdgcn_rcpf(u2), s3=__builtin_amdgcn_rcpf(u3);
        sS += (s0+s1)+(s2+s3);
        sL -= (x.x+__logf(u0)) + (x.y+__logf(u1)) + (x.z+__logf(u2)) + (x.w+__logf(u3));
        const int pos = swpos(k0c, key);
        *(unsigned*)(rS + pos) = pk4_fp8(s0, s1, s2, s3);
        *(unsigned*)(rX + pos) = pk4_fp8(x.x, x.y, x.z, x.w);
    }
    __shared__ float redS[256], redL[256];
    redS[tid] = sS; redL[tid] = sL; __syncthreads();
    for (int s = 128; s > 0; s >>= 1) {
        if (tid < s) { redS[tid] += redS[tid+s]; redL[tid] += redL[tid+s]; }
        __syncthreads();
    }
    if (tid == 0) { sig_rs[n] = redS[0]; l1p_rs[n] = redL[0]; }
}

// K1: resize tgt -> fp8 [T_PAD][25600] (swizzled) + colsum halves. grid (2,T_PAD) x 256.
__global__ void prep_kernel(const float* __restrict__ tm,
                            unsigned char* __restrict__ tf8,
                            float* __restrict__ tgt_sumP) {   // [2][T_PAD]
    const int t = blockIdx.y, q = blockIdx.x, tid = threadIdx.x;
    if (t >= N_TGT) {
        uint4 z = make_uint4(0,0,0,0);
        uint4* dst = (uint4*)(tf8 + (size_t)t * K_TOT + q * 12800);
        for (int i = tid; i < 800; i += 256) dst[i] = z;
        if (tid == 0) tgt_sumP[q * T_PAD + t] = 0.f;
        return;
    }
    const float* src = tm + (size_t)t * (W_IN * W_IN);
    const int key = (t >> 1) & 7;
    float part = 0.f;
    for (int i = tid; i < 3200; i += 256) {
        const int k0c = q * 12800 + i * 4;       // 4 px, same image row
        const int ii = k0c / W_OUT;
        const int j0 = k0c - ii * W_OUT;
        int r0; float wr[4];
        taps(ii, r0, wr);
        float v[4];
        #pragma unroll
        for (int e = 0; e < 4; e++) {
            int c0; float wc[4];
            taps(j0 + e, c0, wc);
            float acc = 0.f;
            #pragma unroll
            for (int a = 0; a < 4; a++) {
                const float* rr = src + (size_t)(r0 + a) * W_IN + c0;
                acc += wr[a] * (wc[0]*rr[0] + wc[1]*rr[1] + wc[2]*rr[2] + wc[3]*rr[3]);
            }
            v[e] = acc;
        }
        part += (v[0] + v[1]) + (v[2] + v[3]);
        *(unsigned*)(tf8 + (size_t)t * K_TOT + swpos(k0c, key)) = pk4_fp8(v[0], v[1], v[2], v[3]);
    }
    __shared__ float red[256];
    red[tid] = part; __syncthreads();
    for (int s = 128; s > 0; s >>= 1) { if (tid < s) red[tid] += red[tid+s]; __syncthreads(); }
    if (tid == 0) tgt_sumP[q * T_PAD + t] = red[0];
}

// ---- K2: fp8 MFMA GEMM, global_load_lds staging, BK=128 ----
#define DECL13(p) f32x4 p##0={0,0,0,0}, p##1={0,0,0,0}, p##2={0,0,0,0}, p##3={0,0,0,0}, \
    p##4={0,0,0,0}, p##5={0,0,0,0}, p##6={0,0,0,0}, p##7={0,0,0,0}, p##8={0,0,0,0}, \
    p##9={0,0,0,0}, p##10={0,0,0,0}, p##11={0,0,0,0}, p##12={0,0,0,0}

#define MFB(tt) { const long bv = *(const long*)&ldsB[bof + (tt)*1024]; \
    accA##tt = __builtin_amdgcn_mfma_f32_16x16x32_fp8_fp8(a0, bv, accA##tt, 0, 0, 0); \
    accB##tt = __builtin_amdgcn_mfma_f32_16x16x32_fp8_fp8(a1, bv, accB##tt, 0, 0, 0); }

// C/D: col=lane&15, row=quad*4+reg. Plane rows interleave: reg parity = plane
// (0=S,1=X) -> float2 {S,X} per pred directly matches combine's P format.
#define EPI(tt) { \
    size_t o0 = base + (size_t)(wave*16 + quad*2) * PROW + 2*((tt)*16 + l16); \
    *(float2*)&P[o0       ] = make_float2(accA##tt[0], accA##tt[1]); \
    *(float2*)&P[o0 + PROW] = make_float2(accA##tt[2], accA##tt[3]); \
    size_t o1 = o0 + 8 * PROW; \
    *(float2*)&P[o1       ] = make_float2(accB##tt[0], accB##tt[1]); \
    *(float2*)&P[o1 + PROW] = make_float2(accB##tt[2], accB##tt[3]); }

__global__ __launch_bounds__(256, 2)
void gemm_kernel(const unsigned char* __restrict__ A2,
                 const unsigned char* __restrict__ tf8,
                 float* __restrict__ P) {
    const int ks = blockIdx.x, mtile = blockIdx.y;
    const int tid = threadIdx.x;
    const int wave = tid >> 6, lane = tid & 63;
    const int quad = lane >> 4, l16 = lane & 15;
    const int kq = (l16 >> 1) & 7;          // swizzle key for this lane's rows

    __shared__ unsigned char ldsA[16384];   // [2 k-halves][128 rows][64]
    __shared__ unsigned char ldsB[26624];   // [2 k-halves][208 rows][64]

    DECL13(accA);   // m-subtile 0 (rows wave*32 + l16)
    DECL13(accB);   // m-subtile 1 (rows wave*32 + 16 + l16)

    const int k0 = ks * K_CHUNK;
    const unsigned char* gA = A2 + (size_t)(mtile * 128) * K_TOT;

    for (int ki = 0; ki < NI; ki++) {
        if (ki) __syncthreads();            // previous MFMA phase done
        const int kb = k0 + ki * BK;
        // A DMA: 1024 x 16B chunks; lds linear = u*16 -> [tb][row][part]
        #pragma unroll
        for (int i = 0; i < 4; i++) {
            const int u = tid + i * 256;
            const int tb = u >> 9, r = (u >> 2) & 127, pt = u & 3;
            gld16(gA + (size_t)r * K_TOT + kb + tb * 64 + pt * 16, &ldsA[u * 16]);
        }
        // B DMA: 1664 chunks
        #pragma unroll
        for (int i = 0; i < 6; i++) {
            const int u = tid + i * 256;
            const int tb = (u >= 832) ? 1 : 0;
            const int um = u - tb * 832;
            gld16(tf8 + (size_t)(um >> 2) * K_TOT + kb + tb * 64 + (u & 3) * 16, &ldsB[u * 16]);
        }
        if (tid < 128) {
            const int u = tid + 1536;
            const int um = u - 832;
            gld16(tf8 + (size_t)(um >> 2) * K_TOT + kb + 64 + (u & 3) * 16, &ldsB[u * 16]);
        }
        __syncthreads();
        // MFMA: A[m=l16][k=quad*8+j], B[t=l16][k=quad*8+j], kk = 4 k-steps of 32
        #pragma unroll
        for (int kk = 0; kk < 4; kk++) {
            const int gsw = ((((kk & 1) * 4 + quad) ^ kq) * 8);
            const int hb = kk >> 1;
            const long a0 = *(const long*)&ldsA[hb * 8192 + (wave * 32      + l16) * 64 + gsw];
            const long a1 = *(const long*)&ldsA[hb * 8192 + (wave * 32 + 16 + l16) * 64 + gsw];
            const int bof = hb * 13312 + l16 * 64 + gsw;
            MFB(0); MFB(1); MFB(2); MFB(3); MFB(4); MFB(5); MFB(6);
            MFB(7); MFB(8); MFB(9); MFB(10); MFB(11); MFB(12);
        }
    }
    const size_t base = ((size_t)(mtile * KS + ks)) * 64 * PROW;
    EPI(0); EPI(1); EPI(2); EPI(3); EPI(4); EPI(5); EPI(6);
    EPI(7); EPI(8); EPI(9); EPI(10); EPI(11); EPI(12);
}

// K3: reduce K-split partials + class/bbox/giou + assemble final cost.
__global__ void combine_kernel(const float* __restrict__ pred_logits,
                               const float* __restrict__ pred_boxes,
                               const int*   __restrict__ tgt_ids,
                               const float* __restrict__ tgt_bbox,
                               const float* __restrict__ P,
                               const float* __restrict__ sig_rs, const float* __restrict__ l1p_rs,
                               const float* __restrict__ tgt_sumP,
                               float* __restrict__ out) {
    const int e = blockIdx.x * 256 + threadIdx.x;
    if (e >= N_PRED * N_TGT) return;
    const int n = e / N_TGT, t = e - n * N_TGT;
    const int mtile = n >> 6, mrow = n & 63;

    const size_t pb = ((size_t)mtile * KS * 64 + mrow) * PROW + 2 * t;
    float s1 = 0.f, s2 = 0.f;
    for (int ks = 0; ks < KS; ks++) {
        float2 v = *(const float2*)&P[pb + (size_t)ks * 64 * PROW];
        s1 += v.x; s2 += v.y;
    }
    const float tsum = tgt_sumP[t] + tgt_sumP[T_PAD + t];
    const float denom = sig_rs[n] + tsum;
    const float cost_dice = -(2.f * s1 + 1.f) / (fmaxf(denom, 1e-6f) + 1.f);
    const float cost_mask = -(s2 + l1p_rs[n]) / (float)HW;
    const int id = tgt_ids[t];
    const float lg = pred_logits[(size_t)n * NCLS + id];
    const float p = 1.f / (1.f + __expf(-lg));
    const float4 ob = *(const float4*)(pred_boxes + (size_t)n * 4);
    const float4 tb = *(const float4*)(tgt_bbox + (size_t)t * 4);
    const float l1 = fabsf(ob.x - tb.x) + fabsf(ob.y - tb.y) + fabsf(ob.z - tb.z) + fabsf(ob.w - tb.w);
    const float ax0 = ob.x - 0.5f*ob.z, ay0 = ob.y - 0.5f*ob.w;
    const float ax1 = ob.x + 0.5f*ob.z, ay1 = ob.y + 0.5f*ob.w;
    const float bx0 = tb.x - 0.5f*tb.z, by0 = tb.y - 0.5f*tb.w;
    const float bx1 = tb.x + 0.5f*tb.z, by1 = tb.y + 0.5f*tb.w;
    const float areaA = (ax1 - ax0) * (ay1 - ay0);
    const float areaB = (bx1 - bx0) * (by1 - by0);
    const float iw = fmaxf(fminf(ax1, bx1) - fmaxf(ax0, bx0), 0.f);
    const float ih = fmaxf(fminf(ay1, by1) - fmaxf(ay0, by0), 0.f);
    const float inter = iw * ih;
    const float uni = areaA + areaB - inter;
    const float iou = inter / uni;
    const float cw = fmaxf(fmaxf(ax1, bx1) - fminf(ax0, bx0), 0.f);
    const float ch = fmaxf(fmaxf(ay1, by1) - fminf(ay0, by0), 0.f);
    const float areaC = cw * ch;
    const float giou = iou - (areaC - uni) / areaC;

    out[e] = 5.f * l1 + 2.f * (-giou) + 2.f * (-p) + 2.f * cost_mask + 2.f * cost_dice;
}

extern "C" void kernel_launch(void* const* d_in, const int* in_sizes, int n_in,
                              void* d_out, int out_size, void* d_ws, size_t ws_size,
                              hipStream_t stream) {
    const float* pred_logits = (const float*)d_in[0];
    const float* pred_boxes  = (const float*)d_in[1];
    const float* pred_masks  = (const float*)d_in[2];
    const int*   tgt_ids     = (const int*)d_in[3];
    const float* tgt_bbox    = (const float*)d_in[4];
    const float* tgt_masks   = (const float*)d_in[5];
    float* out = (float*)d_out;

    // workspace carving (~118 MB of ~491 MB)
    char* ws = (char*)d_ws;
    size_t off = 0;
    unsigned char* tf8 = (unsigned char*)(ws + off);
    off += (size_t)T_PAD * K_TOT;                                 // 5,324,800
    off = (off + 255) & ~(size_t)255;
    unsigned char* A2 = (unsigned char*)(ws + off);
    off += (size_t)MROWS * K_TOT;                                 // 62,259,200
    off = (off + 255) & ~(size_t)255;
    float* tgt_sumP = (float*)(ws + off);                         // [2][208]
    float* sig_rs   = tgt_sumP + 2 * T_PAD;                       // [1200]
    float* l1p_rs   = sig_rs + N_PRED;                            // [1200]
    off += (size_t)(2 * T_PAD + 2 * N_PRED) * sizeof(float);
    off = (off + 255) & ~(size_t)255;
    float* P = (float*)(ws + off);
    off += (size_t)MT * KS * 64 * PROW * sizeof(float);           // 50,585,600

    hipLaunchKernelGGL(conv_kernel, dim3(MROWS / 2), dim3(256), 0, stream,
                       pred_masks, A2, sig_rs, l1p_rs);
    hipLaunchKernelGGL(prep_kernel, dim3(2, T_PAD), dim3(256), 0, stream,
                       tgt_masks, tf8, tgt_sumP);
    hipLaunchKernelGGL(gemm_kernel, dim3(KS, MT), dim3(256), 0, stream,
                       A2, tf8, P);
    hipLaunchKernelGGL(combine_kernel, dim3((N_PRED * N_TGT + 255) / 256), dim3(256), 0, stream,
                       pred_logits, pred_boxes, tgt_ids, tgt_bbox,
                       P, sig_rs, l1p_rs, tgt_sumP, out);
}